// Round 5
// baseline (670.927 us; speedup 1.0000x reference)
//
#include <hip/hip_runtime.h>
#include <cmath>

// ---------------------------------------------------------------------------
// Down_42468636623217 — round 7: single-owner full-line pre_k.
//  r6 post-mortem: store vectorization was a null result (95->91 us) — store
//  issue count was not the bottleneck. Remaining theory: every output cache
//  line was SPLIT 64B/64B between two blocks (cit pairs / jt pairs) on
//  different XCDs -> two partial-line dirty evictions per line + 64-B wave
//  segments. This round merges the 8 (jt,cit) blocks into one block per
//  (i,b): 4 phases of 16 tokens, LDS stages f32 sum/diff pairs (u,v,s,t,
//  [16][133] x4 = 34 KB, 4 blocks/CU), all 8 output streams are exact 2-op
//  combos (numerics identical). Stores: 256 B contiguous per token, >=1 KB
//  per wave, every line single-owner. Halo zeroing folded in.
// ---------------------------------------------------------------------------

#define EPI_NONE 0
#define EPI_GELU 1
#define EPI_GELU_SUB 2
#define EPI_ADD 3
#define EPI_SIGMOID 4
#define EPI_EXP 5

typedef unsigned short u16;
typedef __bf16 v8bf __attribute__((ext_vector_type(8)));
typedef float f32x4 __attribute__((ext_vector_type(4)));

__device__ __forceinline__ float gelu_f(float v) {
  return 0.5f * v * (1.f + erff(v * 0.70710678118654752f));
}
__device__ __forceinline__ float sigmoid_f(float v) {
  return 1.f / (1.f + __expf(-v));
}
__device__ __forceinline__ float bf2f(u16 h) {
  return __uint_as_float((unsigned)h << 16);
}
__device__ __forceinline__ u16 f2bf(float f) {
  unsigned u = __float_as_uint(f);
  return (u16)((u + 0x7fffu + ((u >> 16) & 1u)) >> 16);
}
__device__ __forceinline__ unsigned f2bf_pk(float lo, float hi) {
  unsigned a = __float_as_uint(lo), b = __float_as_uint(hi);
  a = (a + 0x7fffu + ((a >> 16) & 1u)) >> 16;
  b = (b + 0x7fffu + ((b >> 16) & 1u)) >> 16;
  return a | (b << 16);
}
__device__ __forceinline__ void gld_lds16(const void* g, void* l) {
  __builtin_amdgcn_global_load_lds(
      (const __attribute__((address_space(1))) unsigned int*)g,
      (__attribute__((address_space(3))) unsigned int*)l, 16, 0, 0);
}

// --------------------------- DWT + transpose -------------------------------
// Block (i, b) owns the full 64-token x 128-channel tile (rows 2i,2i+1 of x).
// 4 phases of 16 tokens. LDS: u=a+b, v=a-b, s=c+d, t=c-d (f32), from which
// ll=.5(u+s) hl=.5(v+t) lh=.5(u-s) hh=.5(v-t), planes pa=.5(u+v) pb=.5(u-v)
// pc=.5(s+t) pd=.5(s-t) — all exact, single bf16 rounding at pack.
// All global stores: 256 B contiguous per token, single-owner lines.
#define PKST(dst, X, Y, OP)                                                    \
  *(uint4*)(dst) = uint4{                                                      \
      f2bf_pk((X[0] OP Y[0]) * 0.5f, (X[1] OP Y[1]) * 0.5f),                   \
      f2bf_pk((X[2] OP Y[2]) * 0.5f, (X[3] OP Y[3]) * 0.5f),                   \
      f2bf_pk((X[4] OP Y[4]) * 0.5f, (X[5] OP Y[5]) * 0.5f),                   \
      f2bf_pk((X[6] OP Y[6]) * 0.5f, (X[7] OP Y[7]) * 0.5f)};

__global__ __launch_bounds__(256) __attribute__((amdgpu_waves_per_eu(4)))
void pre_k(const float* __restrict__ x, u16* __restrict__ yL16,
           u16* __restrict__ yHHt16, u16* __restrict__ hllh16,
           u16* __restrict__ xpt) {
  int i = blockIdx.x, b = blockIdx.y;
  int tid = threadIdx.x;
  __shared__ float su[16][133], sv[16][133], ss[16][133], st[16][133];
  const float2* x2 = (const float2*)x;
  long tokb = (long)b * 4096 + (long)i * 64;
  long prow = (long)(b * 4) * 4160 + (long)i * 65;  // plane0 row base (x128)
  // zero this row's 4 plane-halo cells (256 B each, full-line)
  if (tid < 64) {
    int ph = tid >> 4, l16 = tid & 15;
    int hc = (ph & 1) ? 0 : 64;
    *(uint4*)(xpt + (prow + (long)ph * 4160 + hc) * 128 + l16 * 8) =
        uint4{0u, 0u, 0u, 0u};
  }
  int txl = tid & 15, tyl = tid >> 4;   // phase-1: token, channel base
  int r2 = tid >> 4, c8 = (tid & 15) * 8;  // phase-2: token, 8-ch chunk
  int ct = tid >> 1, th = (tid & 1) * 8;   // phase-2: yHHt channel, tok oct
  for (int jt = 0; jt < 4; ++jt) {
    int j0 = jt * 16;
    if (jt) __syncthreads();
#pragma unroll
    for (int k = 0; k < 8; ++k) {
      int ch = tyl + 16 * k;
      long base = (((long)(b * 128 + ch) * 128) + 2 * i) * 64 + j0 + txl;
      float2 ab = x2[base];
      float2 cd = x2[base + 64];
      su[txl][ch] = ab.x + ab.y;
      sv[txl][ch] = ab.x - ab.y;
      ss[txl][ch] = cd.x + cd.y;
      st[txl][ch] = cd.x - cd.y;
    }
    __syncthreads();
    float u[8], v[8], s[8], t[8];
#pragma unroll
    for (int e = 0; e < 8; ++e) {
      u[e] = su[r2][c8 + e];
      v[e] = sv[r2][c8 + e];
      s[e] = ss[r2][c8 + e];
      t[e] = st[r2][c8 + e];
    }
    long tg = tokb + j0 + r2;
    int ci = j0 + r2;
    PKST(yL16 + tg * 128 + c8, u, s, +)                      // ll
    PKST(hllh16 + tg * 256 + c8, v, t, +)                    // hl
    PKST(hllh16 + tg * 256 + 128 + c8, u, s, -)              // lh
    PKST(xpt + (prow + ci) * 128 + c8, u, v, +)              // plane0 = a
    PKST(xpt + (prow + 4160 + ci + 1) * 128 + c8, u, v, -)   // plane1 = b
    PKST(xpt + (prow + 8320 + ci) * 128 + c8, s, t, +)       // plane2 = c
    PKST(xpt + (prow + 12480 + ci + 1) * 128 + c8, s, t, -)  // plane3 = d
    // yHHt [c][t]: hh = .5(v - t)
    unsigned hw[4];
#pragma unroll
    for (int q = 0; q < 4; ++q) {
      float h0 = (sv[th + 2 * q][ct] - st[th + 2 * q][ct]) * 0.5f;
      float h1 = (sv[th + 2 * q + 1][ct] - st[th + 2 * q + 1][ct]) * 0.5f;
      hw[q] = f2bf_pk(h0, h1);
    }
    *(uint4*)(yHHt16 + (long)ct * 65536 + tokb + j0 + th) =
        uint4{hw[0], hw[1], hw[2], hw[3]};
  }
}

// ---------------------- weights fp32 -> bf16 (one pass) --------------------
// wall layout (elems): l1w@0(262144, kg-major repack) w1@262144(32768)
//   fc1@294912 div@311296 fc2@327680 fc3a@344064 fc3b@360448 act@376832
// l1w repack: wb2[chunk 32][kg 8][row 128][ke 8]; k = chunk*64 + kg*8 + ke;
// tap order: chunk = stg*4 + sub; stg = kh*2 + cp; sub = kwsel*2 + chalf;
// kw = cp ? (kwsel?2:0) : (kwsel?3:1); c = chalf*64 + (k&63).
// Blocks >= 768 zero the 17-KB row-halo zero page instead.
__global__ __launch_bounds__(256) void wcvt8_k(
    const float* __restrict__ a0, const float* __restrict__ a1,
    const float* __restrict__ a2, const float* __restrict__ a3,
    const float* __restrict__ a4, const float* __restrict__ a5,
    const float* __restrict__ a6, const float* __restrict__ a7,
    unsigned* __restrict__ dst, unsigned* __restrict__ zp) {
  if (blockIdx.x >= 768) {
    zp[(blockIdx.x - 768) * 256 + threadIdx.x] = 0;  // 17 blocks = 17408 B
    return;
  }
  int f = blockIdx.x * 256 + threadIdx.x;  // 196608 uints
  int e = 2 * f;
  if (e < 262144) {
    int ch = e >> 13, kg = (e >> 10) & 7, n = (e >> 3) & 127, ke = e & 7;
    int k = ch * 64 + kg * 8 + ke;
    int stg = ch >> 2, sub = ch & 3;
    int kwsel = sub >> 1, chalf = sub & 1;
    int kh = stg >> 1, cp = stg & 1;
    int kw = cp ? (kwsel ? 2 : 0) : (kwsel ? 3 : 1);
    int c = chalf * 64 + (k & 63);
    long si = (((long)n * 128 + c) * 4 + kh) * 4 + kw;
    dst[f] = f2bf_pk(a0[si], a0[si + 16]);  // k+1 -> c+1 -> +16 floats
    return;
  }
  const float* s; int b;
  if (e < 294912)      { s = a1; b = 262144; }
  else if (e < 311296) { s = a2; b = 294912; }
  else if (e < 327680) { s = a3; b = 311296; }
  else if (e < 344064) { s = a4; b = 327680; }
  else if (e < 360448) { s = a5; b = 344064; }
  else if (e < 376832) { s = a6; b = 360448; }
  else                 { s = a7; b = 376832; }
  dst[f] = f2bf_pk(s[e - b], s[e - b + 1]);
}

// --------------------------- unified bf16 GEMM -----------------------------
// C[m,n] = epi(alpha * sum_k A[m,k]*B[n,k] + bias[n]); A: MxK, B: NxK bf16.
// AMODE 1: A element scaled by sc[z*K + k] (PV: 1/l_k fold).
// Tile 128x128, BK=64, 4 waves 2x2 (each 64x64, 16x16x32 MFMA), XOR-swizzle.
template <int AMODE, int EPI>
__global__ __launch_bounds__(256) void gemm16_k(
    const u16* __restrict__ A, long sA, int lda,
    const u16* __restrict__ B, long sB, int ldb,
    u16* __restrict__ C, long sC, int ldc,
    int K, float alpha, const float* __restrict__ bias,
    const u16* __restrict__ aux, const float* __restrict__ sc) {
  __shared__ __align__(16) char smem[32768];
  char* As = smem;
  char* Bs = smem + 16384;
  int z = blockIdx.z;
  int tid = threadIdx.x, lane = tid & 63, w = tid >> 6;
  int wm = w >> 1, wn = w & 1, l15 = lane & 15, l4 = lane >> 4;
  const u16* Ab = A + (long)z * sA + (long)blockIdx.x * 128 * lda;
  const u16* Bb = B + (long)z * sB + (long)blockIdx.y * 128 * ldb;
  const float* scz = (AMODE == 1) ? sc + (long)z * K : nullptr;
  int sm = tid >> 3, skg = tid & 7;
  int sbase = sm * 128 + ((skg ^ (sm & 7)) << 4);
  uint4 pa[4], pb[4];

  auto loadAB = [&](int k0) {
#pragma unroll
    for (int u = 0; u < 4; ++u) {
      pb[u] = *(const uint4*)(Bb + (long)(sm + 32 * u) * ldb + k0 + skg * 8);
      uint4 v = *(const uint4*)(Ab + (long)(sm + 32 * u) * lda + k0 + skg * 8);
      if (AMODE == 1) {
        float4 s0 = *(const float4*)(scz + k0 + skg * 8);
        float4 s1 = *(const float4*)(scz + k0 + skg * 8 + 4);
        v.x = f2bf_pk(bf2f((u16)(v.x & 0xffff)) * s0.x, bf2f((u16)(v.x >> 16)) * s0.y);
        v.y = f2bf_pk(bf2f((u16)(v.y & 0xffff)) * s0.z, bf2f((u16)(v.y >> 16)) * s0.w);
        v.z = f2bf_pk(bf2f((u16)(v.z & 0xffff)) * s1.x, bf2f((u16)(v.z >> 16)) * s1.y);
        v.w = f2bf_pk(bf2f((u16)(v.w & 0xffff)) * s1.z, bf2f((u16)(v.w >> 16)) * s1.w);
      }
      pa[u] = v;
    }
  };

  f32x4 acc[4][4] = {};
  loadAB(0);
  int nch = K >> 6;
  for (int ch = 0; ch < nch; ++ch) {
    __syncthreads();
#pragma unroll
    for (int u = 0; u < 4; ++u) {
      *(uint4*)(As + sbase + u * 4096) = pa[u];
      *(uint4*)(Bs + sbase + u * 4096) = pb[u];
    }
    __syncthreads();
    if (ch + 1 < nch) loadAB((ch + 1) << 6);
#pragma unroll
    for (int s = 0; s < 2; ++s) {
      int ko = (((s << 2) | l4) ^ (l15 & 7)) << 4;
      v8bf af[4], bfr[4];
#pragma unroll
      for (int t = 0; t < 4; ++t) {
        af[t] = *(const v8bf*)(As + (64 * wm + 16 * t + l15) * 128 + ko);
        bfr[t] = *(const v8bf*)(Bs + (64 * wn + 16 * t + l15) * 128 + ko);
      }
#pragma unroll
      for (int mt = 0; mt < 4; ++mt)
#pragma unroll
        for (int nt = 0; nt < 4; ++nt)
          acc[mt][nt] = __builtin_amdgcn_mfma_f32_16x16x32_bf16(af[mt], bfr[nt], acc[mt][nt], 0, 0, 0);
    }
  }
  // epilogue: C/D layout col = lane&15 (n), row = (lane>>4)*4 + reg (m)
  u16* Cb = C + (long)z * sC;
#pragma unroll
  for (int mt = 0; mt < 4; ++mt) {
#pragma unroll
    for (int nt = 0; nt < 4; ++nt) {
      f32x4 a = acc[mt][nt];
      int n = blockIdx.y * 128 + 64 * wn + 16 * nt + l15;
      float bv = bias ? bias[n] : 0.f;
#pragma unroll
      for (int r = 0; r < 4; ++r) {
        long m = (long)blockIdx.x * 128 + 64 * wm + 16 * mt + 4 * l4 + r;
        float v = a[r] * alpha + bv;
        if (EPI == EPI_GELU) v = gelu_f(v);
        else if (EPI == EPI_GELU_SUB) v = gelu_f(v) - bf2f(aux[m * ldc + n]);
        else if (EPI == EPI_ADD) v += bf2f(aux[m * ldc + n]);
        else if (EPI == EPI_SIGMOID) v = sigmoid_f(v);
        else if (EPI == EPI_EXP) v = __expf(v);
        Cb[m * ldc + n] = f2bf(v);
      }
    }
  }
}

// ------------- conv 4x4 s2 p1: polyphase implicit GEMM (bf16) --------------
// out[b][n][oi][oj] = relu(bias[n] + sum taps). Stage stg = kh*2+cp reads
// plane ph = ((kh+1)&1)<<1 | cp at row oi+roff(kh); padded plane cols make
// slot s <-> storage col s (semantic ci = s - cp), halo cells are zeros.
// A: 65 slots x 256 B, DMA'd (global_load_lds), dbuf, 1 barrier per stage.
// W: direct global->reg fragments from kg-major repack (L1/L2-hot).
__global__ __launch_bounds__(256) __attribute__((amdgpu_waves_per_eu(4)))
void conv4g_k(const u16* __restrict__ xpt, const u16* __restrict__ wb,
              const float* __restrict__ bias, const u16* __restrict__ zp,
              u16* __restrict__ dw16) {
  __shared__ __align__(16) char smem[33280];  // 2 x 16640 A buffers
  char* As = smem;
  // XCD-aware swizzle: 1024 blocks, 8 XCDs -> contiguous 128-block chunks.
  int raw = blockIdx.x;
  int swz = (raw & 7) * 128 + (raw >> 3);
  int oi = swz & 63, b = swz >> 6;
  int tid = threadIdx.x, lane = tid & 63, w = tid >> 6;
  int wm = w >> 1, wn = w & 1, l15 = lane & 15, l4 = lane >> 4;
  f32x4 acc[2][4] = {};

  auto issueA = [&](int stg2, int bsel) {
    int kh = stg2 >> 1, cp2 = stg2 & 1;
    int roff = (kh == 0) ? -1 : (kh == 3) ? 1 : 0;
    int ri = oi + roff;
    int ph = (((kh + 1) & 1) << 1) | cp2;
    const u16* rowb = ((unsigned)ri < 64u)
        ? xpt + ((long)(b * 4 + ph) * 4160 + (long)ri * 65) * 128
        : zp;
    char* lb = As + bsel * 16640 + w * 1024;
#pragma unroll
    for (int i = 0; i < 4; ++i) {
      int d = i * 4096 + w * 1024 + lane * 16;
      int slot = d >> 8, cg = (d >> 4) & 15;
      gld_lds16(rowb + slot * 128 + ((cg ^ ((slot - cp2) & 7)) << 3),
                lb + i * 4096);
    }
    if (tid < 16) {  // last 256 B: slot 64, cg = lane (wave0 lanes 0-15)
      gld_lds16(rowb + 64 * 128 + ((lane ^ ((64 - cp2) & 7)) << 3),
                As + bsel * 16640 + 16384);
    }
  };

  issueA(0, 0);
  for (int stg = 0; stg < 8; ++stg) {
    __syncthreads();  // drains DMA for buf[stg&1]; guards buf reuse
    if (stg < 7) issueA(stg + 1, (stg + 1) & 1);
    const char* Ab = As + (stg & 1) * 16640;
    int cp2 = stg & 1;
#pragma unroll
    for (int sub = 0; sub < 4; ++sub) {
      int chunk = stg * 4 + sub;
      const int kwsel = sub >> 1, chalf = sub & 1;
#pragma unroll
      for (int s = 0; s < 2; ++s) {
        v8bf bw[4], af[2];
#pragma unroll
        for (int nt = 0; nt < 4; ++nt) {
          int row = 64 * wn + 16 * nt + l15;
          bw[nt] = *(const v8bf*)(wb + ((long)(chunk * 8 + s * 4 + l4) * 128 + row) * 8);
        }
#pragma unroll
        for (int mt = 0; mt < 2; ++mt) {
          int slot = 32 * wm + 16 * mt + l15 + kwsel;
          int cg = chalf * 8 + s * 4 + l4;
          af[mt] = *(const v8bf*)(Ab + slot * 256 + ((cg ^ ((slot - cp2) & 7)) << 4));
        }
#pragma unroll
        for (int mt = 0; mt < 2; ++mt)
#pragma unroll
          for (int nt = 0; nt < 4; ++nt)
            acc[mt][nt] = __builtin_amdgcn_mfma_f32_16x16x32_bf16(
                af[mt], bw[nt], acc[mt][nt], 0, 0, 0);
      }
    }
  }
  // epilogue: bias+relu, per-wave LDS transpose, coalesced bf16 stores
  __syncthreads();
  float* buf = (float*)(smem + w * 2176);  // 16 x 34 f32 per wave
  long obase = ((long)b * 128) * 4096 + oi * 64;
#pragma unroll
  for (int cg = 0; cg < 4; ++cg) {
    int co = 64 * wn + 16 * cg + l15;
    float bv = bias[co];
#pragma unroll
    for (int mt = 0; mt < 2; ++mt) {
      f32x4 a = acc[mt][cg];
#pragma unroll
      for (int r = 0; r < 4; ++r)
        buf[l15 * 34 + 16 * mt + 4 * l4 + r] = fmaxf(a[r] + bv, 0.f);
    }
    __syncthreads();
#pragma unroll
    for (int it = 0; it < 8; ++it) {
      int row = it * 2 + (lane >> 5);
      int mcol = lane & 31;
      int coz = 64 * wn + 16 * cg + row;
      dw16[obase + (long)coz * 4096 + 32 * wm + mcol] = f2bf(buf[row * 34 + mcol]);
    }
    __syncthreads();
  }
}

// --------------- attention column normalizer: sc = 1/sum_q E ---------------
__global__ __launch_bounds__(256) void ssum_k(const u16* __restrict__ E,
                                              float* __restrict__ sc) {
  int z = blockIdx.y;
  int k = blockIdx.x * 256 + threadIdx.x;
  const u16* Eb = E + (long)z * 262144 + k;
  float s = 0.f;
#pragma unroll 8
  for (int q = 0; q < 512; ++q) s += bf2f(Eb[(long)q * 512]);
  sc[(long)z * 512 + k] = 1.f / s;
}

// ------------------------------ layernorm (bf16) ---------------------------
__global__ __launch_bounds__(256) void ln16_k(const u16* __restrict__ X,
                                              const float* __restrict__ g,
                                              const float* __restrict__ bt,
                                              const u16* __restrict__ gate,
                                              u16* __restrict__ Y) {
  int t = (blockIdx.x * 256 + threadIdx.x) >> 6;
  int lane = threadIdx.x & 63;
  const u16* xr = X + (long)t * 128;
  float v0 = bf2f(xr[lane]), v1 = bf2f(xr[lane + 64]);
  float s = v0 + v1, sq = v0 * v0 + v1 * v1;
#pragma unroll
  for (int off = 32; off > 0; off >>= 1) {
    s += __shfl_xor(s, off);
    sq += __shfl_xor(sq, off);
  }
  float mean = s * 0.0078125f;
  float var = sq * 0.0078125f - mean * mean;
  float rstd = rsqrtf(var + 1e-5f);
  float y0 = (v0 - mean) * rstd * g[lane] + bt[lane];
  float y1 = (v1 - mean) * rstd * g[lane + 64] + bt[lane + 64];
  if (gate) {
    y0 *= bf2f(gate[(long)t * 128 + lane]);
    y1 *= bf2f(gate[(long)t * 128 + lane + 64]);
  }
  Y[(long)t * 128 + lane] = f2bf(y0);
  Y[(long)t * 128 + lane + 64] = f2bf(y1);
}

// ------------------------------ combine ------------------------------------
__global__ __launch_bounds__(256) void combine_k(const u16* __restrict__ attf,
                                                 const u16* __restrict__ yt,
                                                 const u16* __restrict__ dw16,
                                                 const float* __restrict__ x,
                                                 float* __restrict__ out) {
  int gx = blockIdx.x;  // 2 (jt) * 4 (cot) = 8
  int jt = gx & 1, cot = gx >> 1;
  int i = blockIdx.y, b = blockIdx.z;
  int j0 = jt * 32, co0 = cot * 32;
  int tx = threadIdx.x & 31, ty = threadIdx.x >> 5;
  __shared__ float sa[32][33], sy[32][33];
  long tokbase = (long)b * 4096 + i * 64 + j0;
#pragma unroll
  for (int k = 0; k < 4; ++k) {
    int row = ty + 8 * k;
    long idx = (tokbase + row) * 128 + co0 + tx;
    sa[row][tx] = bf2f(attf[idx]);
    sy[row][tx] = bf2f(yt[idx]);
  }
  __syncthreads();
  float py = (float)(i * 127) / 63.0f;
  int y0 = (int)py;
  int y1 = min(y0 + 1, 127);
  float wy = py - (float)y0;
  int j = j0 + tx;
  float px = (float)(j * 127) / 63.0f;
  int x0 = (int)px;
  int x1 = min(x0 + 1, 127);
  float wx = px - (float)x0;
#pragma unroll
  for (int k = 0; k < 4; ++k) {
    int co = co0 + ty + 8 * k;
    const float* xb = x + (((long)b * 128 + co) * 128) * 128;
    float r0 = xb[y0 * 128 + x0] * (1.f - wx) + xb[y0 * 128 + x1] * wx;
    float r1 = xb[y1 * 128 + x0] * (1.f - wx) + xb[y1 * 128 + x1] * wx;
    float d2 = r0 * (1.f - wy) + r1 * wy;
    long oidx = (((long)b * 128 + co) * 64 + i) * 64 + j;
    float dwv = bf2f(dw16[oidx]);
    out[oidx] = sa[tx][ty + 8 * k] * (d2 - dwv) + sy[tx][ty + 8 * k];
  }
}

// ---------------------------------------------------------------------------
extern "C" void kernel_launch(void* const* d_in, const int* in_sizes, int n_in,
                              void* d_out, int out_size, void* d_ws, size_t ws_size,
                              hipStream_t stream) {
  const float* x = (const float*)d_in[0];
  const float* w1 = (const float*)d_in[1];
  const float* b1 = (const float*)d_in[2];
  const float* l1w = (const float*)d_in[3];
  const float* l1b = (const float*)d_in[4];
  const float* ln1g = (const float*)d_in[5];
  const float* ln1b = (const float*)d_in[6];
  const float* fc1w = (const float*)d_in[7];
  const float* fc1b = (const float*)d_in[8];
  const float* divw = (const float*)d_in[9];
  const float* divb = (const float*)d_in[10];
  const float* fc2w = (const float*)d_in[11];
  const float* fc2b = (const float*)d_in[12];
  const float* ln3g = (const float*)d_in[13];
  const float* ln3b = (const float*)d_in[14];
  const float* fc3aw = (const float*)d_in[15];
  const float* fc3ab = (const float*)d_in[16];
  const float* fc3bw = (const float*)d_in[17];
  const float* fc3bb = (const float*)d_in[18];
  const float* lnng = (const float*)d_in[19];
  const float* lnnb = (const float*)d_in[20];
  const float* actw = (const float*)d_in[21];
  const float* actb = (const float*)d_in[22];

  char* W = (char*)d_ws;
  u16* yL16 = (u16*)(W);
  u16* hllh16 = (u16*)(W + 16777216L);
  u16* yHHt16 = (u16*)(W + 50331648L);
  u16* y16 = (u16*)(W + 67108864L);
  u16* S16 = (u16*)(W + 83886080L);
  u16* attO16 = (u16*)(W + 150994944L);
  u16* dw16 = (u16*)(W + 167772160L);
  u16* t1 = (u16*)(W + 184549376L);
  u16* t2 = (u16*)(W + 201326592L);
  u16* t3 = (u16*)(W + 218103808L);
  u16* t4 = (u16*)(W + 234881024L);
  float* sc = (float*)(W + 251658240L);
  u16* wall = (u16*)(W + 251920384L);
  u16* l1wb = wall;
  u16* w1b = wall + 262144;
  u16* fc1b16 = wall + 294912;
  u16* divb16 = wall + 311296;
  u16* fc2b16 = wall + 327680;
  u16* fc3ab16 = wall + 344064;
  u16* fc3bb16 = wall + 360448;
  u16* actb16 = wall + 376832;
  // polyphase planes: 16b x 4ph x [64 ri][65 ci][128 c] bf16 = 68.16 MB.
  // Lives in the S16 region (dead until the QK GEMM); the last ~1 MB spills
  // into the attO16 region, which is only written after conv4g consumes xpt.
  u16* xpt16 = S16;
  u16* zp16 = (u16*)(W + 152043520L);  // 17408-B zero page (row-OOB reads)

  dim3 blk(256);
  const float qk_scale = 0.35355339059327373f;  // 8^-0.5

  wcvt8_k<<<dim3(785), blk, 0, stream>>>(l1w, w1, fc1w, divw, fc2w, fc3aw,
                                         fc3bw, actw, (unsigned*)wall,
                                         (unsigned*)zp16);
  // 1. DWT + transpose (bf16 outputs incl. yHH^T and padded polyphase planes)
  pre_k<<<dim3(64, 16), blk, 0, stream>>>(x, yL16, yHHt16, hllh16, xpt16);
  // 2. conv1 (1x1, 256->128): y16 = hllh @ w1^T + b1
  gemm16_k<0, EPI_NONE><<<dim3(512, 1, 1), blk, 0, stream>>>(
      hllh16, 0, 256, w1b, 0, 256, y16, 0, 128, 256, 1.f, b1, nullptr, nullptr);
  // 3. conv4x4 stride2 + relu (DMA-staged polyphase implicit GEMM)
  conv4g_k<<<dim3(1024), blk, 0, stream>>>(xpt16, l1wb, l1b, zp16, dw16);
  // 4. E = exp(scale * yL @ y^T)  (softmax numerator; overwrites xpt region)
  gemm16_k<0, EPI_EXP><<<dim3(4, 4, 128), blk, 0, stream>>>(
      yL16, 65536, 128, y16, 65536, 128, S16, 262144, 512, 128, qk_scale,
      nullptr, nullptr, nullptr);
  // 5. sc_k = 1 / sum_q E
  ssum_k<<<dim3(2, 128), blk, 0, stream>>>(S16, sc);
  // 6. attO = (E * sc) @ yHH   (scale folded into A-loader, B = yHH^T rows)
  gemm16_k<1, EPI_NONE><<<dim3(4, 1, 128), blk, 0, stream>>>(
      S16, 262144, 512, yHHt16, 512, 65536, attO16, 65536, 128, 512, 1.f,
      nullptr, nullptr, sc);
  // 7. FFN
  ln16_k<<<16384, blk, 0, stream>>>(attO16, ln1g, ln1b, nullptr, t1);
  gemm16_k<0, EPI_GELU><<<dim3(512, 1, 1), blk, 0, stream>>>(
      t1, 0, 128, fc1b16, 0, 128, t2, 0, 128, 128, 1.f, fc1b, nullptr, nullptr);
  gemm16_k<0, EPI_GELU_SUB><<<dim3(512, 1, 1), blk, 0, stream>>>(
      attO16, 0, 128, divb16, 0, 128, t3, 0, 128, 128, 1.f, divb, t2, nullptr);
  gemm16_k<0, EPI_GELU><<<dim3(512, 1, 1), blk, 0, stream>>>(
      t3, 0, 128, fc2b16, 0, 128, t4, 0, 128, 128, 1.f, fc2b, nullptr, nullptr);
  ln16_k<<<16384, blk, 0, stream>>>(attO16, ln3g, ln3b, nullptr, t1);
  gemm16_k<0, EPI_GELU><<<dim3(512, 1, 1), blk, 0, stream>>>(
      t1, 0, 128, fc3ab16, 0, 128, t3, 0, 128, 128, 1.f, fc3ab, nullptr, nullptr);
  gemm16_k<0, EPI_ADD><<<dim3(512, 1, 1), blk, 0, stream>>>(
      t3, 0, 128, fc3bb16, 0, 128, t1, 0, 128, 128, 1.f, fc3bb, t4, nullptr);
  gemm16_k<0, EPI_SIGMOID><<<dim3(512, 1, 1), blk, 0, stream>>>(
      attO16, 0, 128, actb16, 0, 128, t3, 0, 128, 128, 1.f, actb, nullptr, nullptr);
  ln16_k<<<16384, blk, 0, stream>>>(t1, lnng, lnnb, t3, t2);
  // 8. combine: out = attf * (resize(x) - dw) + y
  combine_k<<<dim3(8, 64, 16), blk, 0, stream>>>(t2, y16, dw16, x, (float*)d_out);
}

// Round 6
// 609.991 us; speedup vs baseline: 1.0999x; 1.0999x over previous
//
#include <hip/hip_runtime.h>
#include <cmath>

// ---------------------------------------------------------------------------
// Down_42468636623217 — round 8: fused persistent-tile FFN.
//  r7 post-mortem: single-owner pre_k was a null (pre_k pinned at ~2.1 TB/s
//  across 3 structural rewrites -> near its practical limit; reverted to the
//  r6 version, best measured). New target: the FFN chain (3 ln16 + 6 gemm16
//  + t1..t4 HBM round-trips ~ 320 MB for 13 GFLOP). ffn_k fuses the whole
//  chain per 64-token tile: 3 x 16 KB swizzled LDS buffers (X, A, E),
//  global_load_lds staging with pre-swizzled source, MFMA GEMMs with
//  B-fragments read straight from the L2-hot bf16 weight pack, identical
//  bf16 rounding points to the unfused chain. 16.8 MB in + 16.8 MB out.
// ---------------------------------------------------------------------------

#define EPI_NONE 0
#define EPI_EXP 5

typedef unsigned short u16;
typedef __bf16 v8bf __attribute__((ext_vector_type(8)));
typedef float f32x4 __attribute__((ext_vector_type(4)));

__device__ __forceinline__ float gelu_f(float v) {
  return 0.5f * v * (1.f + erff(v * 0.70710678118654752f));
}
__device__ __forceinline__ float sigmoid_f(float v) {
  return 1.f / (1.f + __expf(-v));
}
__device__ __forceinline__ float bf2f(u16 h) {
  return __uint_as_float((unsigned)h << 16);
}
__device__ __forceinline__ u16 f2bf(float f) {
  unsigned u = __float_as_uint(f);
  return (u16)((u + 0x7fffu + ((u >> 16) & 1u)) >> 16);
}
__device__ __forceinline__ unsigned f2bf_pk(float lo, float hi) {
  unsigned a = __float_as_uint(lo), b = __float_as_uint(hi);
  a = (a + 0x7fffu + ((a >> 16) & 1u)) >> 16;
  b = (b + 0x7fffu + ((b >> 16) & 1u)) >> 16;
  return a | (b << 16);
}
__device__ __forceinline__ void gld_lds16(const void* g, void* l) {
  __builtin_amdgcn_global_load_lds(
      (const __attribute__((address_space(1))) unsigned int*)g,
      (__attribute__((address_space(3))) unsigned int*)l, 16, 0, 0);
}

// --------------------------- DWT + transpose (r6 version) ------------------
// x NCHW fp32 -> yL16 [t][c], hllh16 [t][256], yHHt16 [c][t], and padded
// polyphase planes xpt[b][ph][64 ri][65 ci][128 c] bf16 (linear channels).
__global__ __launch_bounds__(256) void pre_k(const float* __restrict__ x,
                                             u16* __restrict__ yL16,
                                             u16* __restrict__ yHHt16,
                                             u16* __restrict__ hllh16,
                                             u16* __restrict__ xpt) {
  int gx = blockIdx.x;  // 2 (jt) * 4 (ci tile) = 8
  int jt = gx & 1, cit = gx >> 1;
  int i = blockIdx.y, b = blockIdx.z;
  int j0 = jt * 32, ci0 = cit * 32;
  int tx = threadIdx.x & 31, ty = threadIdx.x >> 5;
  __shared__ float sll[32][33], shl[32][33], slh[32][33], shh[32][33];
  // zero halo columns (one block pair per (b, i))
  if (gx == 0) {
    int pl = 1 + ((threadIdx.x >> 7) << 1);  // planes 1,3: storage col 0
    long off = ((long)(b * 4 + pl) * 4160 + (long)i * 65) * 128 + (threadIdx.x & 127);
    xpt[off] = 0;
  } else if (gx == 1) {
    int pl = (threadIdx.x >> 7) << 1;        // planes 0,2: storage col 64
    long off = ((long)(b * 4 + pl) * 4160 + (long)i * 65 + 64) * 128 + (threadIdx.x & 127);
    xpt[off] = 0;
  }
  const float2* x2 = (const float2*)x;
#pragma unroll
  for (int k = 0; k < 4; ++k) {
    int ci = ty + 8 * k;
    long base = (((long)b * 128 + ci0 + ci) * 128 + 2 * i) * 64 + j0 + tx;
    float2 ab = x2[base];
    float2 cd = x2[base + 64];
    float a = ab.x, bb = ab.y, c = cd.x, d = cd.y;
    sll[ci][tx] = (a + bb + c + d) * 0.5f;
    shl[ci][tx] = (a - bb + c - d) * 0.5f;
    slh[ci][tx] = (a + bb - c - d) * 0.5f;
    shh[ci][tx] = (a - bb - c + d) * 0.5f;
  }
  __syncthreads();
  long tok = (long)b * 4096 + i * 64 + j0;
  int r = threadIdx.x >> 3;         // token col offset 0..31
  int q4 = (threadIdx.x & 7) << 2;  // channel offset 0,4,..,28
  float vll[4], vhl[4], vlh[4], vhh[4];
#pragma unroll
  for (int e = 0; e < 4; ++e) {
    vll[e] = sll[q4 + e][r];
    vhl[e] = shl[q4 + e][r];
    vlh[e] = slh[q4 + e][r];
    vhh[e] = shh[q4 + e][r];
  }
  uint2 u;
  u.x = f2bf_pk(vll[0], vll[1]);
  u.y = f2bf_pk(vll[2], vll[3]);
  *(uint2*)(yL16 + (tok + r) * 128 + ci0 + q4) = u;
  u.x = f2bf_pk(vhl[0], vhl[1]);
  u.y = f2bf_pk(vhl[2], vhl[3]);
  *(uint2*)(hllh16 + (tok + r) * 256 + ci0 + q4) = u;
  u.x = f2bf_pk(vlh[0], vlh[1]);
  u.y = f2bf_pk(vlh[2], vlh[3]);
  *(uint2*)(hllh16 + (tok + r) * 256 + 128 + ci0 + q4) = u;
  {
    int ch = threadIdx.x >> 3;        // channel offset 0..31
    int t4 = (threadIdx.x & 7) << 2;  // token offset 0,4,..,28
    uint2 h;
    h.x = f2bf_pk(shh[ch][t4], shh[ch][t4 + 1]);
    h.y = f2bf_pk(shh[ch][t4 + 2], shh[ch][t4 + 3]);
    *(uint2*)(yHHt16 + (long)(ci0 + ch) * 65536 + tok + t4) = h;
  }
  {
    long rb = (long)(b * 4) * 4160 + (long)i * 65;  // plane0 row base (x128)
    int ci = j0 + r;
    float pA[4], pB[4], pC[4], pD[4];
#pragma unroll
    for (int e = 0; e < 4; ++e) {
      pA[e] = 0.5f * (vll[e] + vhl[e] + vlh[e] + vhh[e]);
      pB[e] = 0.5f * (vll[e] - vhl[e] + vlh[e] - vhh[e]);
      pC[e] = 0.5f * (vll[e] + vhl[e] - vlh[e] - vhh[e]);
      pD[e] = 0.5f * (vll[e] - vhl[e] - vlh[e] + vhh[e]);
    }
    u.x = f2bf_pk(pA[0], pA[1]);
    u.y = f2bf_pk(pA[2], pA[3]);
    *(uint2*)(xpt + (rb + ci) * 128 + ci0 + q4) = u;
    u.x = f2bf_pk(pB[0], pB[1]);
    u.y = f2bf_pk(pB[2], pB[3]);
    *(uint2*)(xpt + (rb + 4160 + ci + 1) * 128 + ci0 + q4) = u;
    u.x = f2bf_pk(pC[0], pC[1]);
    u.y = f2bf_pk(pC[2], pC[3]);
    *(uint2*)(xpt + (rb + 8320 + ci) * 128 + ci0 + q4) = u;
    u.x = f2bf_pk(pD[0], pD[1]);
    u.y = f2bf_pk(pD[2], pD[3]);
    *(uint2*)(xpt + (rb + 12480 + ci + 1) * 128 + ci0 + q4) = u;
  }
}

// ---------------------- weights fp32 -> bf16 (one pass) --------------------
__global__ __launch_bounds__(256) void wcvt8_k(
    const float* __restrict__ a0, const float* __restrict__ a1,
    const float* __restrict__ a2, const float* __restrict__ a3,
    const float* __restrict__ a4, const float* __restrict__ a5,
    const float* __restrict__ a6, const float* __restrict__ a7,
    unsigned* __restrict__ dst, unsigned* __restrict__ zp) {
  if (blockIdx.x >= 768) {
    zp[(blockIdx.x - 768) * 256 + threadIdx.x] = 0;  // 17 blocks = 17408 B
    return;
  }
  int f = blockIdx.x * 256 + threadIdx.x;  // 196608 uints
  int e = 2 * f;
  if (e < 262144) {
    int ch = e >> 13, kg = (e >> 10) & 7, n = (e >> 3) & 127, ke = e & 7;
    int k = ch * 64 + kg * 8 + ke;
    int stg = ch >> 2, sub = ch & 3;
    int kwsel = sub >> 1, chalf = sub & 1;
    int kh = stg >> 1, cp = stg & 1;
    int kw = cp ? (kwsel ? 2 : 0) : (kwsel ? 3 : 1);
    int c = chalf * 64 + (k & 63);
    long si = (((long)n * 128 + c) * 4 + kh) * 4 + kw;
    dst[f] = f2bf_pk(a0[si], a0[si + 16]);  // k+1 -> c+1 -> +16 floats
    return;
  }
  const float* s; int b;
  if (e < 294912)      { s = a1; b = 262144; }
  else if (e < 311296) { s = a2; b = 294912; }
  else if (e < 327680) { s = a3; b = 311296; }
  else if (e < 344064) { s = a4; b = 327680; }
  else if (e < 360448) { s = a5; b = 344064; }
  else if (e < 376832) { s = a6; b = 360448; }
  else                 { s = a7; b = 376832; }
  dst[f] = f2bf_pk(s[e - b], s[e - b + 1]);
}

// --------------------------- unified bf16 GEMM -----------------------------
// (still used for: conv1 1x1, QK softmax-numerator, PV)
template <int AMODE, int EPI>
__global__ __launch_bounds__(256) void gemm16_k(
    const u16* __restrict__ A, long sA, int lda,
    const u16* __restrict__ B, long sB, int ldb,
    u16* __restrict__ C, long sC, int ldc,
    int K, float alpha, const float* __restrict__ bias,
    const u16* __restrict__ aux, const float* __restrict__ sc) {
  __shared__ __align__(16) char smem[32768];
  char* As = smem;
  char* Bs = smem + 16384;
  int z = blockIdx.z;
  int tid = threadIdx.x, lane = tid & 63, w = tid >> 6;
  int wm = w >> 1, wn = w & 1, l15 = lane & 15, l4 = lane >> 4;
  const u16* Ab = A + (long)z * sA + (long)blockIdx.x * 128 * lda;
  const u16* Bb = B + (long)z * sB + (long)blockIdx.y * 128 * ldb;
  const float* scz = (AMODE == 1) ? sc + (long)z * K : nullptr;
  int sm = tid >> 3, skg = tid & 7;
  int sbase = sm * 128 + ((skg ^ (sm & 7)) << 4);
  uint4 pa[4], pb[4];

  auto loadAB = [&](int k0) {
#pragma unroll
    for (int u = 0; u < 4; ++u) {
      pb[u] = *(const uint4*)(Bb + (long)(sm + 32 * u) * ldb + k0 + skg * 8);
      uint4 v = *(const uint4*)(Ab + (long)(sm + 32 * u) * lda + k0 + skg * 8);
      if (AMODE == 1) {
        float4 s0 = *(const float4*)(scz + k0 + skg * 8);
        float4 s1 = *(const float4*)(scz + k0 + skg * 8 + 4);
        v.x = f2bf_pk(bf2f((u16)(v.x & 0xffff)) * s0.x, bf2f((u16)(v.x >> 16)) * s0.y);
        v.y = f2bf_pk(bf2f((u16)(v.y & 0xffff)) * s0.z, bf2f((u16)(v.y >> 16)) * s0.w);
        v.z = f2bf_pk(bf2f((u16)(v.z & 0xffff)) * s1.x, bf2f((u16)(v.z >> 16)) * s1.y);
        v.w = f2bf_pk(bf2f((u16)(v.w & 0xffff)) * s1.z, bf2f((u16)(v.w >> 16)) * s1.w);
      }
      pa[u] = v;
    }
  };

  f32x4 acc[4][4] = {};
  loadAB(0);
  int nch = K >> 6;
  for (int ch = 0; ch < nch; ++ch) {
    __syncthreads();
#pragma unroll
    for (int u = 0; u < 4; ++u) {
      *(uint4*)(As + sbase + u * 4096) = pa[u];
      *(uint4*)(Bs + sbase + u * 4096) = pb[u];
    }
    __syncthreads();
    if (ch + 1 < nch) loadAB((ch + 1) << 6);
#pragma unroll
    for (int s = 0; s < 2; ++s) {
      int ko = (((s << 2) | l4) ^ (l15 & 7)) << 4;
      v8bf af[4], bfr[4];
#pragma unroll
      for (int t = 0; t < 4; ++t) {
        af[t] = *(const v8bf*)(As + (64 * wm + 16 * t + l15) * 128 + ko);
        bfr[t] = *(const v8bf*)(Bs + (64 * wn + 16 * t + l15) * 128 + ko);
      }
#pragma unroll
      for (int mt = 0; mt < 4; ++mt)
#pragma unroll
        for (int nt = 0; nt < 4; ++nt)
          acc[mt][nt] = __builtin_amdgcn_mfma_f32_16x16x32_bf16(af[mt], bfr[nt], acc[mt][nt], 0, 0, 0);
    }
  }
  u16* Cb = C + (long)z * sC;
#pragma unroll
  for (int mt = 0; mt < 4; ++mt) {
#pragma unroll
    for (int nt = 0; nt < 4; ++nt) {
      f32x4 a = acc[mt][nt];
      int n = blockIdx.y * 128 + 64 * wn + 16 * nt + l15;
      float bv = bias ? bias[n] : 0.f;
#pragma unroll
      for (int r = 0; r < 4; ++r) {
        long m = (long)blockIdx.x * 128 + 64 * wm + 16 * mt + 4 * l4 + r;
        float v = a[r] * alpha + bv;
        if (EPI == EPI_EXP) v = __expf(v);
        Cb[m * ldc + n] = f2bf(v);
      }
    }
  }
}

// --------------------------- fused FFN -------------------------------------
// Per 64-token tile (1024 blocks): X = attO tile; chain
//  E = gelu(ln1(X)@fc1); A = gelu(X@div)-E; E = gelu(A@fc2);        (E = x2)
//  A = ln3(X); A = gelu(A@fc3a); A = A@fc3b + E;                    (x2+x3)
//  E = sigmoid(X@act); out = lnn(A) * E.
// LDS: 3 x [64 rows][16 granules x 16B] bf16, XOR-swizzled (granule^(row&7)).
// B-operands read directly from the L2-hot bf16 weight pack (N=128 x K=128).
// bf16 rounding points identical to the unfused chain.
__global__ __launch_bounds__(256) void ffn_k(
    const u16* __restrict__ Xg,
    const u16* __restrict__ w_fc1, const u16* __restrict__ w_div,
    const u16* __restrict__ w_fc2, const u16* __restrict__ w_fc3a,
    const u16* __restrict__ w_fc3b, const u16* __restrict__ w_act,
    const float* __restrict__ b_fc1, const float* __restrict__ b_div,
    const float* __restrict__ b_fc2, const float* __restrict__ b_fc3a,
    const float* __restrict__ b_fc3b, const float* __restrict__ b_act,
    const float* __restrict__ ln1g, const float* __restrict__ ln1b,
    const float* __restrict__ ln3g, const float* __restrict__ ln3b,
    const float* __restrict__ lnng, const float* __restrict__ lnnb,
    u16* __restrict__ out) {
  __shared__ __align__(16) char smem[49152];
  char* X = smem;
  char* A = smem + 16384;
  char* E = smem + 32768;
  int z = blockIdx.x;
  long t0 = (long)z * 64;
  int tid = threadIdx.x, lane = tid & 63, w = tid >> 6;
  int wm = w >> 1, wn = w & 1, l15 = lane & 15, l4 = lane >> 4;

  // stage X with pre-swizzled global source (LDS dest linear; m173 pattern)
  {
    const u16* src = Xg + t0 * 128;
#pragma unroll
    for (int r = 0; r < 4; ++r) {
      int u = r * 256 + tid;
      int row = u >> 4, cg = u & 15;
      gld_lds16(src + row * 128 + ((cg ^ (row & 7)) << 3),
                X + (r * 256 + w * 64) * 16);
    }
  }

  // GEMM: acc += Asrc(64x128, swizzled LDS) @ Bg(128x128 N-major)^T
  auto gemm = [&](const char* Asrc, const u16* Bg, f32x4 (&acc)[2][4]) {
#pragma unroll
    for (int mt = 0; mt < 2; ++mt)
#pragma unroll
      for (int nt = 0; nt < 4; ++nt) acc[mt][nt] = f32x4{0.f, 0.f, 0.f, 0.f};
#pragma unroll
    for (int s = 0; s < 4; ++s) {
      v8bf af[2], bw[4];
#pragma unroll
      for (int mt = 0; mt < 2; ++mt) {
        int row = 32 * wm + 16 * mt + l15;
        af[mt] = *(const v8bf*)(Asrc + row * 256 + (((s * 4 + l4) ^ (row & 7)) << 4));
      }
#pragma unroll
      for (int nt = 0; nt < 4; ++nt) {
        int rn = 64 * wn + 16 * nt + l15;
        bw[nt] = *(const v8bf*)(Bg + rn * 128 + (s * 4 + l4) * 8);
      }
#pragma unroll
      for (int mt = 0; mt < 2; ++mt)
#pragma unroll
        for (int nt = 0; nt < 4; ++nt)
          acc[mt][nt] = __builtin_amdgcn_mfma_f32_16x16x32_bf16(
              af[mt], bw[nt], acc[mt][nt], 0, 0, 0);
    }
  };

  // epilogue: mode 0 = gelu, 1 = gelu(v) - E, 2 = v + E, 3 = sigmoid
  auto epi = [&](f32x4 (&acc)[2][4], const float* bias, char* dst,
                 const char* Eb, int mode) {
#pragma unroll
    for (int nt = 0; nt < 4; ++nt) {
      int n = 64 * wn + 16 * nt + l15;
      float bv = bias[n];
#pragma unroll
      for (int mt = 0; mt < 2; ++mt) {
#pragma unroll
        for (int r = 0; r < 4; ++r) {
          int m = 32 * wm + 16 * mt + 4 * l4 + r;
          int off = m * 256 + (((n >> 3) ^ (m & 7)) << 4) + (n & 7) * 2;
          float v = acc[mt][nt][r] + bv;
          if (mode == 0) v = gelu_f(v);
          else if (mode == 1) v = gelu_f(v) - bf2f(*(const u16*)(Eb + off));
          else if (mode == 2) v += bf2f(*(const u16*)(Eb + off));
          else v = sigmoid_f(v);
          *(u16*)(dst + off) = f2bf(v);
        }
      }
    }
  };

  // layernorm pass: src (bf16, swizzled LDS) -> dst; 16 rows/wave, 4 lanes/row
  auto lnpass = [&](const char* src, char* dst, const float* g,
                    const float* bt) {
    int row = w * 16 + (lane >> 2), q = lane & 3;
    float v[32];
    float s = 0.f, sq = 0.f;
#pragma unroll
    for (int gi = 0; gi < 4; ++gi) {
      int gr = q * 4 + gi;
      v8bf hv = *(const v8bf*)(src + row * 256 + ((gr ^ (row & 7)) << 4));
#pragma unroll
      for (int e = 0; e < 8; ++e) {
        float f = bf2f(((const u16*)&hv)[e]);
        v[gi * 8 + e] = f;
        s += f;
        sq += f * f;
      }
    }
    s += __shfl_xor(s, 1); sq += __shfl_xor(sq, 1);
    s += __shfl_xor(s, 2); sq += __shfl_xor(sq, 2);
    float mean = s * 0.0078125f;
    float rstd = rsqrtf(sq * 0.0078125f - mean * mean + 1e-5f);
#pragma unroll
    for (int gi = 0; gi < 4; ++gi) {
      int gr = q * 4 + gi;
      int c0 = gr * 8;
      unsigned o[4];
#pragma unroll
      for (int e = 0; e < 4; ++e) {
        float y0 = (v[gi * 8 + 2 * e] - mean) * rstd * g[c0 + 2 * e] + bt[c0 + 2 * e];
        float y1 = (v[gi * 8 + 2 * e + 1] - mean) * rstd * g[c0 + 2 * e + 1] + bt[c0 + 2 * e + 1];
        o[e] = f2bf_pk(y0, y1);
      }
      *(uint4*)(dst + row * 256 + ((gr ^ (row & 7)) << 4)) = *(uint4*)o;
    }
  };

  f32x4 acc[2][4];
  __syncthreads();                       // X staged (barrier drains DMA)
  lnpass(X, A, ln1g, ln1b); __syncthreads();
  gemm(A, w_fc1, acc); __syncthreads();
  epi(acc, b_fc1, E, nullptr, 0); __syncthreads();   // E = x1
  gemm(X, w_div, acc); __syncthreads();
  epi(acc, b_div, A, E, 1); __syncthreads();         // A = gelu(X@div)-x1
  gemm(A, w_fc2, acc); __syncthreads();
  epi(acc, b_fc2, E, nullptr, 0); __syncthreads();   // E = x2
  lnpass(X, A, ln3g, ln3b); __syncthreads();
  gemm(A, w_fc3a, acc); __syncthreads();
  epi(acc, b_fc3a, A, nullptr, 0); __syncthreads();  // A = h (in-place ok)
  gemm(A, w_fc3b, acc); __syncthreads();
  epi(acc, b_fc3b, A, E, 2); __syncthreads();        // A = x2 + x3
  gemm(X, w_act, acc); __syncthreads();
  epi(acc, b_act, E, nullptr, 3); __syncthreads();   // E = gate

  // final: out = lnn(A) * E, written straight to global
  {
    int row = w * 16 + (lane >> 2), q = lane & 3;
    float v[32];
    float s = 0.f, sq = 0.f;
#pragma unroll
    for (int gi = 0; gi < 4; ++gi) {
      int gr = q * 4 + gi;
      v8bf hv = *(const v8bf*)(A + row * 256 + ((gr ^ (row & 7)) << 4));
#pragma unroll
      for (int e = 0; e < 8; ++e) {
        float f = bf2f(((const u16*)&hv)[e]);
        v[gi * 8 + e] = f;
        s += f;
        sq += f * f;
      }
    }
    s += __shfl_xor(s, 1); sq += __shfl_xor(sq, 1);
    s += __shfl_xor(s, 2); sq += __shfl_xor(sq, 2);
    float mean = s * 0.0078125f;
    float rstd = rsqrtf(sq * 0.0078125f - mean * mean + 1e-5f);
    u16* og = out + (t0 + row) * 128;
#pragma unroll
    for (int gi = 0; gi < 4; ++gi) {
      int gr = q * 4 + gi;
      int c0 = gr * 8;
      v8bf gv = *(const v8bf*)(E + row * 256 + ((gr ^ (row & 7)) << 4));
      unsigned o[4];
#pragma unroll
      for (int e = 0; e < 4; ++e) {
        float y0 = ((v[gi * 8 + 2 * e] - mean) * rstd * lnng[c0 + 2 * e] + lnnb[c0 + 2 * e]) *
                   bf2f(((const u16*)&gv)[2 * e]);
        float y1 = ((v[gi * 8 + 2 * e + 1] - mean) * rstd * lnng[c0 + 2 * e + 1] + lnnb[c0 + 2 * e + 1]) *
                   bf2f(((const u16*)&gv)[2 * e + 1]);
        o[e] = f2bf_pk(y0, y1);
      }
      *(uint4*)(og + c0) = *(uint4*)o;
    }
  }
}

// ------------- conv 4x4 s2 p1: polyphase implicit GEMM (bf16) --------------
__global__ __launch_bounds__(256) __attribute__((amdgpu_waves_per_eu(4)))
void conv4g_k(const u16* __restrict__ xpt, const u16* __restrict__ wb,
              const float* __restrict__ bias, const u16* __restrict__ zp,
              u16* __restrict__ dw16) {
  __shared__ __align__(16) char smem[33280];  // 2 x 16640 A buffers
  char* As = smem;
  int raw = blockIdx.x;
  int swz = (raw & 7) * 128 + (raw >> 3);
  int oi = swz & 63, b = swz >> 6;
  int tid = threadIdx.x, lane = tid & 63, w = tid >> 6;
  int wm = w >> 1, wn = w & 1, l15 = lane & 15, l4 = lane >> 4;
  f32x4 acc[2][4] = {};

  auto issueA = [&](int stg2, int bsel) {
    int kh = stg2 >> 1, cp2 = stg2 & 1;
    int roff = (kh == 0) ? -1 : (kh == 3) ? 1 : 0;
    int ri = oi + roff;
    int ph = (((kh + 1) & 1) << 1) | cp2;
    const u16* rowb = ((unsigned)ri < 64u)
        ? xpt + ((long)(b * 4 + ph) * 4160 + (long)ri * 65) * 128
        : zp;
    char* lb = As + bsel * 16640 + w * 1024;
#pragma unroll
    for (int i = 0; i < 4; ++i) {
      int d = i * 4096 + w * 1024 + lane * 16;
      int slot = d >> 8, cg = (d >> 4) & 15;
      gld_lds16(rowb + slot * 128 + ((cg ^ ((slot - cp2) & 7)) << 3),
                lb + i * 4096);
    }
    if (tid < 16) {
      gld_lds16(rowb + 64 * 128 + ((lane ^ ((64 - cp2) & 7)) << 3),
                As + bsel * 16640 + 16384);
    }
  };

  issueA(0, 0);
  for (int stg = 0; stg < 8; ++stg) {
    __syncthreads();
    if (stg < 7) issueA(stg + 1, (stg + 1) & 1);
    const char* Ab = As + (stg & 1) * 16640;
    int cp2 = stg & 1;
#pragma unroll
    for (int sub = 0; sub < 4; ++sub) {
      int chunk = stg * 4 + sub;
      const int kwsel = sub >> 1, chalf = sub & 1;
#pragma unroll
      for (int s = 0; s < 2; ++s) {
        v8bf bw[4], af[2];
#pragma unroll
        for (int nt = 0; nt < 4; ++nt) {
          int row = 64 * wn + 16 * nt + l15;
          bw[nt] = *(const v8bf*)(wb + ((long)(chunk * 8 + s * 4 + l4) * 128 + row) * 8);
        }
#pragma unroll
        for (int mt = 0; mt < 2; ++mt) {
          int slot = 32 * wm + 16 * mt + l15 + kwsel;
          int cg = chalf * 8 + s * 4 + l4;
          af[mt] = *(const v8bf*)(Ab + slot * 256 + ((cg ^ ((slot - cp2) & 7)) << 4));
        }
#pragma unroll
        for (int mt = 0; mt < 2; ++mt)
#pragma unroll
          for (int nt = 0; nt < 4; ++nt)
            acc[mt][nt] = __builtin_amdgcn_mfma_f32_16x16x32_bf16(
                af[mt], bw[nt], acc[mt][nt], 0, 0, 0);
      }
    }
  }
  __syncthreads();
  float* buf = (float*)(smem + w * 2176);  // 16 x 34 f32 per wave
  long obase = ((long)b * 128) * 4096 + oi * 64;
#pragma unroll
  for (int cg = 0; cg < 4; ++cg) {
    int co = 64 * wn + 16 * cg + l15;
    float bv = bias[co];
#pragma unroll
    for (int mt = 0; mt < 2; ++mt) {
      f32x4 a = acc[mt][cg];
#pragma unroll
      for (int r = 0; r < 4; ++r)
        buf[l15 * 34 + 16 * mt + 4 * l4 + r] = fmaxf(a[r] + bv, 0.f);
    }
    __syncthreads();
#pragma unroll
    for (int it = 0; it < 8; ++it) {
      int row = it * 2 + (lane >> 5);
      int mcol = lane & 31;
      int coz = 64 * wn + 16 * cg + row;
      dw16[obase + (long)coz * 4096 + 32 * wm + mcol] = f2bf(buf[row * 34 + mcol]);
    }
    __syncthreads();
  }
}

// --------------- attention column normalizer: sc = 1/sum_q E ---------------
__global__ __launch_bounds__(256) void ssum_k(const u16* __restrict__ E,
                                              float* __restrict__ sc) {
  int z = blockIdx.y;
  int k = blockIdx.x * 256 + threadIdx.x;
  const u16* Eb = E + (long)z * 262144 + k;
  float s = 0.f;
#pragma unroll 8
  for (int q = 0; q < 512; ++q) s += bf2f(Eb[(long)q * 512]);
  sc[(long)z * 512 + k] = 1.f / s;
}

// ------------------------------ combine ------------------------------------
__global__ __launch_bounds__(256) void combine_k(const u16* __restrict__ attf,
                                                 const u16* __restrict__ yt,
                                                 const u16* __restrict__ dw16,
                                                 const float* __restrict__ x,
                                                 float* __restrict__ out) {
  int gx = blockIdx.x;  // 2 (jt) * 4 (cot) = 8
  int jt = gx & 1, cot = gx >> 1;
  int i = blockIdx.y, b = blockIdx.z;
  int j0 = jt * 32, co0 = cot * 32;
  int tx = threadIdx.x & 31, ty = threadIdx.x >> 5;
  __shared__ float sa[32][33], sy[32][33];
  long tokbase = (long)b * 4096 + i * 64 + j0;
#pragma unroll
  for (int k = 0; k < 4; ++k) {
    int row = ty + 8 * k;
    long idx = (tokbase + row) * 128 + co0 + tx;
    sa[row][tx] = bf2f(attf[idx]);
    sy[row][tx] = bf2f(yt[idx]);
  }
  __syncthreads();
  float py = (float)(i * 127) / 63.0f;
  int y0 = (int)py;
  int y1 = min(y0 + 1, 127);
  float wy = py - (float)y0;
  int j = j0 + tx;
  float px = (float)(j * 127) / 63.0f;
  int x0 = (int)px;
  int x1 = min(x0 + 1, 127);
  float wx = px - (float)x0;
#pragma unroll
  for (int k = 0; k < 4; ++k) {
    int co = co0 + ty + 8 * k;
    const float* xb = x + (((long)b * 128 + co) * 128) * 128;
    float r0 = xb[y0 * 128 + x0] * (1.f - wx) + xb[y0 * 128 + x1] * wx;
    float r1 = xb[y1 * 128 + x0] * (1.f - wx) + xb[y1 * 128 + x1] * wx;
    float d2 = r0 * (1.f - wy) + r1 * wy;
    long oidx = (((long)b * 128 + co) * 64 + i) * 64 + j;
    float dwv = bf2f(dw16[oidx]);
    out[oidx] = sa[tx][ty + 8 * k] * (d2 - dwv) + sy[tx][ty + 8 * k];
  }
}

// ---------------------------------------------------------------------------
extern "C" void kernel_launch(void* const* d_in, const int* in_sizes, int n_in,
                              void* d_out, int out_size, void* d_ws, size_t ws_size,
                              hipStream_t stream) {
  const float* x = (const float*)d_in[0];
  const float* w1 = (const float*)d_in[1];
  const float* b1 = (const float*)d_in[2];
  const float* l1w = (const float*)d_in[3];
  const float* l1b = (const float*)d_in[4];
  const float* ln1g = (const float*)d_in[5];
  const float* ln1b = (const float*)d_in[6];
  const float* fc1w = (const float*)d_in[7];
  const float* fc1b = (const float*)d_in[8];
  const float* divw = (const float*)d_in[9];
  const float* divb = (const float*)d_in[10];
  const float* fc2w = (const float*)d_in[11];
  const float* fc2b = (const float*)d_in[12];
  const float* ln3g = (const float*)d_in[13];
  const float* ln3b = (const float*)d_in[14];
  const float* fc3aw = (const float*)d_in[15];
  const float* fc3ab = (const float*)d_in[16];
  const float* fc3bw = (const float*)d_in[17];
  const float* fc3bb = (const float*)d_in[18];
  const float* lnng = (const float*)d_in[19];
  const float* lnnb = (const float*)d_in[20];
  const float* actw = (const float*)d_in[21];
  const float* actb = (const float*)d_in[22];

  char* W = (char*)d_ws;
  u16* yL16 = (u16*)(W);
  u16* hllh16 = (u16*)(W + 16777216L);
  u16* yHHt16 = (u16*)(W + 50331648L);
  u16* y16 = (u16*)(W + 67108864L);
  u16* S16 = (u16*)(W + 83886080L);
  u16* attO16 = (u16*)(W + 150994944L);
  u16* dw16 = (u16*)(W + 167772160L);
  u16* t2 = (u16*)(W + 201326592L);
  float* sc = (float*)(W + 251658240L);
  u16* wall = (u16*)(W + 251920384L);
  u16* l1wb = wall;
  u16* w1b = wall + 262144;
  u16* fc1b16 = wall + 294912;
  u16* divb16 = wall + 311296;
  u16* fc2b16 = wall + 327680;
  u16* fc3ab16 = wall + 344064;
  u16* fc3bb16 = wall + 360448;
  u16* actb16 = wall + 376832;
  u16* xpt16 = S16;  // polyphase planes live in S16 region until QK GEMM
  u16* zp16 = (u16*)(W + 152043520L);  // 17408-B zero page (row-OOB reads)

  dim3 blk(256);
  const float qk_scale = 0.35355339059327373f;  // 8^-0.5

  wcvt8_k<<<dim3(785), blk, 0, stream>>>(l1w, w1, fc1w, divw, fc2w, fc3aw,
                                         fc3bw, actw, (unsigned*)wall,
                                         (unsigned*)zp16);
  // 1. DWT + transpose (bf16 outputs incl. yHH^T and padded polyphase planes)
  pre_k<<<dim3(8, 64, 16), blk, 0, stream>>>(x, yL16, yHHt16, hllh16, xpt16);
  // 2. conv1 (1x1, 256->128): y16 = hllh @ w1^T + b1
  gemm16_k<0, EPI_NONE><<<dim3(512, 1, 1), blk, 0, stream>>>(
      hllh16, 0, 256, w1b, 0, 256, y16, 0, 128, 256, 1.f, b1, nullptr, nullptr);
  // 3. conv4x4 stride2 + relu (DMA-staged polyphase implicit GEMM)
  conv4g_k<<<dim3(1024), blk, 0, stream>>>(xpt16, l1wb, l1b, zp16, dw16);
  // 4. E = exp(scale * yL @ y^T)  (softmax numerator; overwrites xpt region)
  gemm16_k<0, EPI_EXP><<<dim3(4, 4, 128), blk, 0, stream>>>(
      yL16, 65536, 128, y16, 65536, 128, S16, 262144, 512, 128, qk_scale,
      nullptr, nullptr, nullptr);
  // 5. sc_k = 1 / sum_q E
  ssum_k<<<dim3(2, 128), blk, 0, stream>>>(S16, sc);
  // 6. attO = (E * sc) @ yHH   (scale folded into A-loader, B = yHH^T rows)
  gemm16_k<1, EPI_NONE><<<dim3(4, 1, 128), blk, 0, stream>>>(
      S16, 262144, 512, yHHt16, 512, 65536, attO16, 65536, 128, 512, 1.f,
      nullptr, nullptr, sc);
  // 7. fused FFN: attO -> t2 (replaces 3 ln16 + 6 gemm16 + t1/t3/t4 traffic)
  ffn_k<<<dim3(1024), blk, 0, stream>>>(
      attO16, fc1b16, divb16, fc2b16, fc3ab16, fc3bb16, actb16,
      fc1b, divb, fc2b, fc3ab, fc3bb, actb,
      ln1g, ln1b, ln3g, ln3b, lnng, lnnb, t2);
  // 8. combine: out = attf * (resize(x) - dw) + y
  combine_k<<<dim3(8, 64, 16), blk, 0, stream>>>(t2, y16, dw16, x, (float*)d_out);
}